// Round 1
// baseline (415.614 us; speedup 1.0000x reference)
//
#include <hip/hip_runtime.h>
#include <stdint.h>

// DuelingQNet fused kernel, bf16 MFMA (16x16x32), BT=16 rows/block, 256 threads.
// Dims: B=65536, O=256, Z=9, D=H=128, L=4, M=4, A=8. Output fp32 (B,8).

typedef __attribute__((ext_vector_type(8))) short short8;   // 8 x bf16 fragment (4 VGPRs)
typedef __attribute__((ext_vector_type(4))) float f32x4;    // C/D fragment

__device__ __forceinline__ unsigned short f2bf(float f) {
  union { float f; uint32_t u; } v; v.f = f;
  uint32_t r = v.u + 0x7FFFu + ((v.u >> 16) & 1u);   // RNE
  return (unsigned short)(r >> 16);
}
__device__ __forceinline__ float bf2f(unsigned short h) {
  union { uint32_t u; float f; } v; v.u = ((uint32_t)h) << 16;
  return v.f;
}

// ---- weight pre-transpose: fp32 [d][e] -> bf16 [e][d] into workspace ----
// ws layout (ushort elems): WbT [128][256] @ 0 ; WmT [16][128][128] @ 32768 ; Wa1T [128][128] @ 294912
__global__ void prep_weights(const float* __restrict__ Wb, const float* __restrict__ Wm,
                             const float* __restrict__ Wa1, unsigned short* __restrict__ ws) {
  int idx = blockIdx.x * 256 + threadIdx.x;
  if (idx < 32768) {
    int e = idx >> 8, d = idx & 255;
    ws[idx] = f2bf(Wb[d * 128 + e]);
  } else if (idx < 294912) {
    int t = idx - 32768;
    int lj = t >> 14, r = t & 16383;
    int e = r >> 7, d = r & 127;
    ws[idx] = f2bf(Wm[lj * 16384 + d * 128 + e]);
  } else if (idx < 311296) {
    int t = idx - 294912;
    int e = t >> 7, d = t & 127;
    ws[idx] = f2bf(Wa1[d * 128 + e]);
  }
}

// Stage one K-64 slice of a pre-transposed weight [128 n][rowLen d] into
// WL[2][128][32] (fragment-major: cc*4096 + n*32 + kk). idx decomposes exactly.
__device__ __forceinline__ void stage_B(unsigned short* WL, const unsigned short* __restrict__ src,
                                        int rowLen, int kOff, int tid) {
#pragma unroll
  for (int it = 0; it < 4; ++it) {
    int idx = it * 2048 + tid * 8;
    int n = (idx >> 5) & 127, cc = idx >> 12, kk = idx & 31;
    *(short8*)(WL + idx) = *(const short8*)(src + n * rowLen + kOff + cc * 32 + kk);
  }
}

__global__ __launch_bounds__(256, 2) void dueling_fused(
    const float* __restrict__ o, const float* __restrict__ zmap, const float* __restrict__ coll,
    const float* __restrict__ bb, const float* __restrict__ Wz, const float* __restrict__ bz,
    const float* __restrict__ bm, const float* __restrict__ Wg, const float* __restrict__ Wgl,
    const float* __restrict__ Wv, const float* __restrict__ bv,
    const float* __restrict__ ba1, const float* __restrict__ Wa2, const float* __restrict__ ba2,
    const unsigned short* __restrict__ WbT, const unsigned short* __restrict__ WmT,
    const unsigned short* __restrict__ Wa1T, float* __restrict__ out)
{
  __shared__ __align__(16) unsigned char smem[55104];
  unsigned short* xA     = (unsigned short*)(smem);            // [4][16][136] bf16 module states
  unsigned short* WL     = (unsigned short*)(smem + 17408);    // [2][128][32] bf16 B-frag staging
  float*          WLf    = (float*)(smem + 17408);             // f32 view for small weights
  unsigned short* xinb   = (unsigned short*)(smem + 33792);    // [16][136] bf16: f0 -> xin -> a1
  float*          gbuf   = (float*)(smem + 38144);             // [16][132] f32 routing embedding
  unsigned short* featb  = (unsigned short*)(smem + 46592);    // [16][136] bf16 feature
  float*          pall   = (float*)(smem + 50944);             // [3][16][16] routing probs
  float*          plastb = (float*)(smem + 54016);             // [16][4]
  float*          zbuf   = (float*)(smem + 54272);             // [16][12]
  float*          vbuf   = (float*)(smem + 55040);             // [16] value head
  unsigned short* obuf   = (unsigned short*)(smem);            // alias xA: [16][72] o-chunk

  const int tid  = threadIdx.x;
  const int wv   = tid >> 6;          // wave 0..3 -> N-slice wv*32
  const int lane = tid & 63;
  const int q    = lane >> 4;         // quad
  const int ml   = lane & 15;         // A-row / B-col / C-col
  const int row0 = blockIdx.x * 16;

  // z_in staging: [z_map | collision]
  if (tid < 144)      { int r = tid / 9, c = tid - r * 9; zbuf[r * 12 + c] = zmap[(row0 + r) * 9 + c]; }
  else if (tid < 160) { int r = tid - 144; zbuf[r * 12 + 9] = coll[row0 + r]; }

  // ---- Phase 1: f0 = relu(o @ Wb + bb) ----
  f32x4 fa0 = {0.f, 0.f, 0.f, 0.f}, fa1 = {0.f, 0.f, 0.f, 0.f};
  {
    const int r = tid >> 4, c4 = (tid & 15) * 4;
    for (int kc = 0; kc < 4; ++kc) {
      float4 ovv = *(const float4*)(o + (size_t)(row0 + r) * 256 + kc * 64 + c4);
      unsigned short* dst = obuf + r * 72 + c4;
      dst[0] = f2bf(ovv.x); dst[1] = f2bf(ovv.y); dst[2] = f2bf(ovv.z); dst[3] = f2bf(ovv.w);
      stage_B(WL, WbT, 256, kc * 64, tid);
      __syncthreads();
#pragma unroll
      for (int cc = 0; cc < 2; ++cc) {
        short8 av = *(const short8*)(obuf + ml * 72 + cc * 32 + q * 8);
        short8 b0 = *(const short8*)(WL + cc * 4096 + (wv * 32 + ml) * 32 + q * 8);
        short8 b1 = *(const short8*)(WL + cc * 4096 + (wv * 32 + 16 + ml) * 32 + q * 8);
        fa0 = __builtin_amdgcn_mfma_f32_16x16x32_bf16(av, b0, fa0, 0, 0, 0);
        fa1 = __builtin_amdgcn_mfma_f32_16x16x32_bf16(av, b1, fa1, 0, 0, 0);
      }
      __syncthreads();
    }
  }
  // f0 epilogue: C/D frag is col=lane&15(+tile), row=quad*4+reg  [m89/m91]
  float f0v[2][4];
  {
#pragma unroll
    for (int nt = 0; nt < 2; ++nt) {
      int col = wv * 32 + nt * 16 + ml;
      float bbv = bb[col];
#pragma unroll
      for (int r2 = 0; r2 < 4; ++r2) {
        float vv = (nt == 0 ? fa0[r2] : fa1[r2]) + bbv;
        vv = vv > 0.f ? vv : 0.f;
        f0v[nt][r2] = vv;
        xinb[(q * 4 + r2) * 136 + col] = f2bf(vv);
      }
    }
  }
  __syncthreads();

  // ---- Phase 2: g = relu(z_in @ Wz + bz) * f0 (fp32) ----
  for (int idx = tid; idx < 1280; idx += 256) WLf[idx] = Wz[idx];
  __syncthreads();
#pragma unroll
  for (int nt = 0; nt < 2; ++nt) {
    int col = wv * 32 + nt * 16 + ml;
    float bzv = bz[col];
#pragma unroll
    for (int r2 = 0; r2 < 4; ++r2) {
      int row = q * 4 + r2;
      float zd = bzv;
#pragma unroll
      for (int k = 0; k < 10; ++k) zd += zbuf[row * 12 + k] * WLf[k * 128 + col];
      gbuf[row * 132 + col] = (zd > 0.f ? zd : 0.f) * f0v[nt][r2];
    }
  }
  __syncthreads();

  // ---- Phase 3: all routing softmaxes up front ----
  for (int idx = tid; idx < 6144; idx += 256) WL[idx] = f2bf(Wg[idx]);
  for (int idx = tid; idx < 512;  idx += 256) WL[6144 + idx] = f2bf(Wgl[idx]);
  __syncthreads();
  if (tid < 192) {       // (layer li, row r, out-module j): softmax over incoming i
    int li = tid >> 6, r = (tid >> 2) & 15, j = tid & 3;
    float a0 = 0.f, a1 = 0.f, a2 = 0.f, a3 = 0.f;
    for (int d = 0; d < 128; ++d) {
      float gv = gbuf[r * 132 + d];
      const unsigned short* wrow = WL + li * 2048 + d * 16 + j;
      a0 += gv * bf2f(wrow[0]);  a1 += gv * bf2f(wrow[4]);
      a2 += gv * bf2f(wrow[8]);  a3 += gv * bf2f(wrow[12]);
    }
    float mx = fmaxf(fmaxf(a0, a1), fmaxf(a2, a3));
    float e0 = expf(a0 - mx), e1 = expf(a1 - mx), e2 = expf(a2 - mx), e3 = expf(a3 - mx);
    float inv = 1.f / (e0 + e1 + e2 + e3);
    float* pd = pall + li * 256 + r * 16 + j;
    pd[0] = e0 * inv; pd[4] = e1 * inv; pd[8] = e2 * inv; pd[12] = e3 * inv;
  } else if (tid < 208) { // p_last per row
    int r = tid - 192;
    float a0 = 0.f, a1 = 0.f, a2 = 0.f, a3 = 0.f;
    for (int d = 0; d < 128; ++d) {
      float gv = gbuf[r * 132 + d];
      const unsigned short* wrow = WL + 6144 + d * 4;
      a0 += gv * bf2f(wrow[0]); a1 += gv * bf2f(wrow[1]);
      a2 += gv * bf2f(wrow[2]); a3 += gv * bf2f(wrow[3]);
    }
    float mx = fmaxf(fmaxf(a0, a1), fmaxf(a2, a3));
    float e0 = expf(a0 - mx), e1 = expf(a1 - mx), e2 = expf(a2 - mx), e3 = expf(a3 - mx);
    float inv = 1.f / (e0 + e1 + e2 + e3);
    plastb[r * 4 + 0] = e0 * inv; plastb[r * 4 + 1] = e1 * inv;
    plastb[r * 4 + 2] = e2 * inv; plastb[r * 4 + 3] = e3 * inv;
  }
  __syncthreads();

  // ---- Phase 4/5: L module layers; accs for all 4 modules live in regs ----
  f32x4 acc[4][2];
  for (int l = 0; l < 4; ++l) {
#pragma unroll
    for (int j = 0; j < 4; ++j) {
      acc[j][0] = fa0 - fa0;  // zero
      acc[j][1] = acc[j][0];
    }
    for (int j = 0; j < 4; ++j) {
      const unsigned short* wsrc = WmT + (l * 4 + j) * 16384;
      for (int st = 0; st < 2; ++st) {
        if (st == 0 && l > 0) {
          // cooperative xin_j[r][d] = sum_i p[r][i][j] * x[i][r][d]
          int r = tid >> 4, d8 = (tid & 15) * 8;
          const float* pr = pall + (l - 1) * 256 + r * 16 + j;
          float p0 = pr[0], p1 = pr[4], p2 = pr[8], p3 = pr[12];
          short8 x0 = *(const short8*)(xA + 0 * 2176 + r * 136 + d8);
          short8 x1 = *(const short8*)(xA + 1 * 2176 + r * 136 + d8);
          short8 x2 = *(const short8*)(xA + 2 * 2176 + r * 136 + d8);
          short8 x3 = *(const short8*)(xA + 3 * 2176 + r * 136 + d8);
          union { short8 v; unsigned short u[8]; } pk;
#pragma unroll
          for (int e = 0; e < 8; ++e) {
            float s = p0 * bf2f((unsigned short)x0[e]) + p1 * bf2f((unsigned short)x1[e])
                    + p2 * bf2f((unsigned short)x2[e]) + p3 * bf2f((unsigned short)x3[e]);
            pk.u[e] = f2bf(s);
          }
          *(short8*)(xinb + r * 136 + d8) = pk.v;
        }
        stage_B(WL, wsrc, 128, st * 64, tid);
        __syncthreads();
#pragma unroll
        for (int cc = 0; cc < 2; ++cc) {
          short8 av = *(const short8*)(xinb + ml * 136 + st * 64 + cc * 32 + q * 8);
          short8 b0 = *(const short8*)(WL + cc * 4096 + (wv * 32 + ml) * 32 + q * 8);
          short8 b1 = *(const short8*)(WL + cc * 4096 + (wv * 32 + 16 + ml) * 32 + q * 8);
          acc[j][0] = __builtin_amdgcn_mfma_f32_16x16x32_bf16(av, b0, acc[j][0], 0, 0, 0);
          acc[j][1] = __builtin_amdgcn_mfma_f32_16x16x32_bf16(av, b1, acc[j][1], 0, 0, 0);
        }
        __syncthreads();
      }
    }
    // bias + relu; write x back to xA (not needed after last layer)
#pragma unroll
    for (int j = 0; j < 4; ++j) {
#pragma unroll
      for (int nt = 0; nt < 2; ++nt) {
        int col = wv * 32 + nt * 16 + ml;
        float bmv = bm[(l * 4 + j) * 128 + col];
#pragma unroll
        for (int r2 = 0; r2 < 4; ++r2) {
          float vv = acc[j][nt][r2] + bmv;
          vv = vv > 0.f ? vv : 0.f;
          acc[j][nt][r2] = vv;
          if (l < 3) xA[j * 2176 + (q * 4 + r2) * 136 + col] = f2bf(vv);
        }
      }
    }
    __syncthreads();
  }

  // ---- Phase 6: feature = sum_j p_last[j] * x3[j] ----
#pragma unroll
  for (int nt = 0; nt < 2; ++nt) {
    int col = wv * 32 + nt * 16 + ml;
#pragma unroll
    for (int r2 = 0; r2 < 4; ++r2) {
      int row = q * 4 + r2;
      float s = plastb[row * 4 + 0] * acc[0][nt][r2] + plastb[row * 4 + 1] * acc[1][nt][r2]
              + plastb[row * 4 + 2] * acc[2][nt][r2] + plastb[row * 4 + 3] * acc[3][nt][r2];
      featb[row * 136 + col] = f2bf(s);
    }
  }
  __syncthreads();

  // ---- Phase 7: heads ----
  if (tid < 128) WLf[tid] = Wv[tid];
  if (tid == 128) WLf[128] = bv[0];
  __syncthreads();
  if (tid < 16) {
    float a = WLf[128];
    for (int d = 0; d < 128; ++d) a += bf2f(featb[tid * 136 + d]) * WLf[d];
    vbuf[tid] = a;
  }
  __syncthreads();
  f32x4 aa0 = fa0 - fa0, aa1 = aa0;
  for (int st = 0; st < 2; ++st) {
    stage_B(WL, Wa1T, 128, st * 64, tid);
    __syncthreads();
#pragma unroll
    for (int cc = 0; cc < 2; ++cc) {
      short8 av = *(const short8*)(featb + ml * 136 + st * 64 + cc * 32 + q * 8);
      short8 b0 = *(const short8*)(WL + cc * 4096 + (wv * 32 + ml) * 32 + q * 8);
      short8 b1 = *(const short8*)(WL + cc * 4096 + (wv * 32 + 16 + ml) * 32 + q * 8);
      aa0 = __builtin_amdgcn_mfma_f32_16x16x32_bf16(av, b0, aa0, 0, 0, 0);
      aa1 = __builtin_amdgcn_mfma_f32_16x16x32_bf16(av, b1, aa1, 0, 0, 0);
    }
    __syncthreads();
  }
#pragma unroll
  for (int nt = 0; nt < 2; ++nt) {
    int col = wv * 32 + nt * 16 + ml;
    float b1v = ba1[col];
#pragma unroll
    for (int r2 = 0; r2 < 4; ++r2) {
      float vv = (nt == 0 ? aa0[r2] : aa1[r2]) + b1v;
      vv = vv > 0.f ? vv : 0.f;
      xinb[(q * 4 + r2) * 136 + col] = f2bf(vv);   // a1
    }
  }
  __syncthreads();
  for (int idx = tid; idx < 1024; idx += 256) WLf[idx] = Wa2[idx];
  if (tid < 8) WLf[1024 + tid] = ba2[tid];
  __syncthreads();
  if (tid < 128) {
    int r = tid >> 3, k = tid & 7;
    float a = WLf[1024 + k];
    for (int d = 0; d < 128; ++d) a += bf2f(xinb[r * 136 + d]) * WLf[d * 8 + k];
    float s = a;
    s += __shfl_xor(s, 1);
    s += __shfl_xor(s, 2);
    s += __shfl_xor(s, 4);
    out[(size_t)(row0 + r) * 8 + k] = a - s * 0.125f + vbuf[r];
  }
}

extern "C" void kernel_launch(void* const* d_in, const int* in_sizes, int n_in,
                              void* d_out, int out_size, void* d_ws, size_t ws_size,
                              hipStream_t stream) {
  const float* o   = (const float*)d_in[0];
  const float* zm  = (const float*)d_in[1];
  const float* cp  = (const float*)d_in[2];
  const float* Wb  = (const float*)d_in[3];
  const float* bb  = (const float*)d_in[4];
  const float* Wz  = (const float*)d_in[5];
  const float* bz  = (const float*)d_in[6];
  const float* Wm  = (const float*)d_in[7];
  const float* bm  = (const float*)d_in[8];
  const float* Wg  = (const float*)d_in[9];
  const float* Wgl = (const float*)d_in[10];
  const float* Wv  = (const float*)d_in[11];
  const float* bv  = (const float*)d_in[12];
  const float* Wa1 = (const float*)d_in[13];
  const float* ba1 = (const float*)d_in[14];
  const float* Wa2 = (const float*)d_in[15];
  const float* ba2 = (const float*)d_in[16];
  unsigned short* wsT = (unsigned short*)d_ws;

  int B = in_sizes[0] / 256;   // 65536

  hipLaunchKernelGGL(prep_weights, dim3(1216), dim3(256), 0, stream, Wb, Wm, Wa1, wsT);
  hipLaunchKernelGGL(dueling_fused, dim3(B / 16), dim3(256), 0, stream,
                     o, zm, cp, bb, Wz, bz, bm, Wg, Wgl, Wv, bv, ba1, Wa2, ba2,
                     wsT, wsT + 32768, wsT + 294912, (float*)d_out);
}

// Round 2
// 343.739 us; speedup vs baseline: 1.2091x; 1.2091x over previous
//
#include <hip/hip_runtime.h>
#include <stdint.h>

// DuelingQNet fused, bf16 MFMA 16x16x32. BT=64 rows/block, 256 thr (4 waves,
// M-split: wave wv owns rows wv*16..wv*16+15). x lives in registers as bf16
// A-fragments; routing combine is register-only VALU. Weights pre-shuffled to
// fragment-linear layout by prep kernel; staged whole (128x128) per module
// into padded LDS (stride 40 shorts -> 2-way bank = free, 16B aligned).
// Dims: B=65536, O=256, Z=9, D=H=128, L=4, M=4, A=8. fp32 in/out.

typedef __attribute__((ext_vector_type(8))) short short8;  // bf16x8 frag (4 VGPR)
typedef __attribute__((ext_vector_type(4))) float f32x4;   // MFMA C/D frag

__device__ __forceinline__ unsigned short f2bf(float f) {
  union { float f; uint32_t u; } v; v.f = f;
  uint32_t r = v.u + 0x7FFFu + ((v.u >> 16) & 1u);  // RNE
  return (unsigned short)(r >> 16);
}
__device__ __forceinline__ float blo(uint32_t w) { union { uint32_t u; float f; } c; c.u = w << 16; return c.f; }
__device__ __forceinline__ float bhi(uint32_t w) { union { uint32_t u; float f; } c; c.u = w & 0xffff0000u; return c.f; }
__device__ __forceinline__ uint32_t packrne(float lo, float hi) {
  union { float f; uint32_t u; } a, b; a.f = lo; b.f = hi;
  uint32_t ra = a.u + 0x7fffu + ((a.u >> 16) & 1u);
  uint32_t rb = b.u + 0x7fffu + ((b.u >> 16) & 1u);
  return (ra >> 16) | (rb & 0xffff0000u);
}
union S8 { short8 s; uint32_t u[4]; };

// ---- prep: fp32 weights -> bf16 fragment-linear [st][n][32] in workspace ----
// ushort offsets: WbF[8][128][32]@0  WmF 16x[4][128][32]@32768  Wa1F[4][128][32]@294912
//                 WgF[4][64][32]@311296 (n=li*16+i*4+j | 48+m | pad0)  Wa2F[4][16][32]@319488
__global__ void prep_weights(const float* __restrict__ Wb, const float* __restrict__ Wm,
                             const float* __restrict__ Wa1, const float* __restrict__ Wg,
                             const float* __restrict__ Wgl, const float* __restrict__ Wa2,
                             unsigned short* __restrict__ ws) {
  int idx = blockIdx.x * 256 + threadIdx.x;
  if (idx >= 321536) return;
  unsigned short v;
  if (idx < 32768) {
    int st = idx >> 12, n = (idx >> 5) & 127, kk = idx & 31;
    v = f2bf(Wb[(st * 32 + kk) * 128 + n]);
  } else if (idx < 294912) {
    int t = idx - 32768; int lj = t >> 14; int g = t & 16383;
    int st = g >> 12, n = (g >> 5) & 127, kk = g & 31;
    v = f2bf(Wm[lj * 16384 + (st * 32 + kk) * 128 + n]);
  } else if (idx < 311296) {
    int t = idx - 294912; int st = t >> 12, n = (t >> 5) & 127, kk = t & 31;
    v = f2bf(Wa1[(st * 32 + kk) * 128 + n]);
  } else if (idx < 319488) {
    int t = idx - 311296; int st = t >> 11, n = (t >> 5) & 63, kk = t & 31;
    int k = st * 32 + kk;
    if (n < 48)      v = f2bf(Wg[(n >> 4) * 2048 + k * 16 + (n & 15)]);
    else if (n < 52) v = f2bf(Wgl[k * 4 + (n - 48)]);
    else             v = 0;
  } else {
    int t = idx - 319488; int st = t >> 9, n = (t >> 5) & 15, kk = t & 31;
    v = (n < 8) ? f2bf(Wa2[(st * 32 + kk) * 8 + n]) : (unsigned short)0;
  }
  ws[idx] = v;
}

// stage frag-linear global [4st][N][32] -> LDS padded [(st*N+n)*40 + q*8]
template <int N>
__device__ __forceinline__ void stage_W(unsigned short* WLs, const unsigned short* __restrict__ src, int tid) {
#pragma unroll
  for (int r = 0; r < N / 16; ++r) {
    int g = r * 2048 + tid * 8;
    int q = (g >> 3) & 3, n = (g >> 5) % N, st = g / (32 * N);
    short8 v = *(const short8*)(src + g);
    *(short8*)(WLs + (st * N + n) * 40 + q * 8) = v;
  }
}

__global__ __launch_bounds__(256, 2) void dueling_fused(
    const float* __restrict__ o, const float* __restrict__ zmap, const float* __restrict__ coll,
    const float* __restrict__ bb, const float* __restrict__ Wz, const float* __restrict__ bz,
    const float* __restrict__ bm, const float* __restrict__ Wv, const float* __restrict__ bv,
    const float* __restrict__ ba1, const float* __restrict__ ba2,
    const unsigned short* __restrict__ WbF, const unsigned short* __restrict__ WmF,
    const unsigned short* __restrict__ Wa1F, const unsigned short* __restrict__ WgF,
    const unsigned short* __restrict__ Wa2F, float* __restrict__ out)
{
  // LDS 65536 B exactly: WL 40960 | xbuf 17408 | pall 6144 (ovl zbuf, Wv) | plast 1024 (ovl vbuf)
  __shared__ __align__(16) unsigned char smem[65536];
  unsigned short* WL    = (unsigned short*)(smem);
  float*          WLf   = (float*)(smem);               // fp32 overlay (Wz)
  unsigned short* xbuf  = (unsigned short*)(smem + 40960);  // per-wave [16][136] bf16
  unsigned short* pall  = (unsigned short*)(smem + 58368);  // [3][64][16] bf16, idx j*4+i
  float*          zbufF = (float*)(smem + 58368);           // [64][12] (dead before pall)
  float*          WvF   = (float*)(smem + 58368);           // [129]    (after pall dead)
  float*          plast = (float*)(smem + 64512);           // [64][4]
  float*          vbuf  = (float*)(smem + 64512);           // [64]     (after plast dead)

  const int tid = threadIdx.x;
  const int wv  = tid >> 6;
  const int lane = tid & 63;
  const int q   = lane >> 4;     // quad: A-frag k chunk / C-frag row group
  const int ml  = lane & 15;     // A-row / B-col / C-col
  const int row0 = blockIdx.x * 64;
  unsigned short* xbw = xbuf + wv * 2176;   // wave-private [16][136]

  // z_in staging
  for (int i = tid; i < 640; i += 256) {
    if (i < 576) { int r = i / 9, c = i - r * 9; zbufF[r * 12 + c] = zmap[(row0 + r) * 9 + c]; }
    else         { int r = i - 576; zbufF[r * 12 + 9] = coll[row0 + r]; }
  }

  const f32x4 z4 = {0.f, 0.f, 0.f, 0.f};

  // ---- Phase 1: f0 = relu(o @ Wb + bb), K=256 in two halves ----
  f32x4 acc[8];
#pragma unroll
  for (int nt = 0; nt < 8; ++nt) acc[nt] = z4;
  const float* orow = o + (size_t)(row0 + wv * 16 + ml) * 256;
#pragma unroll
  for (int kh = 0; kh < 2; ++kh) {
    float4 ov[8];
#pragma unroll
    for (int st = 0; st < 4; ++st) {
      const float* src = orow + kh * 128 + st * 32 + q * 8;
      ov[st * 2]     = *(const float4*)(src);
      ov[st * 2 + 1] = *(const float4*)(src + 4);
    }
    if (kh) __syncthreads();
    stage_W<128>(WL, WbF + kh * 16384, tid);
    __syncthreads();
#pragma unroll
    for (int st = 0; st < 4; ++st) {
      S8 af;
      af.u[0] = packrne(ov[st*2].x, ov[st*2].y);  af.u[1] = packrne(ov[st*2].z, ov[st*2].w);
      af.u[2] = packrne(ov[st*2+1].x, ov[st*2+1].y); af.u[3] = packrne(ov[st*2+1].z, ov[st*2+1].w);
#pragma unroll
      for (int nt = 0; nt < 8; ++nt) {
        short8 bf = *(const short8*)(WL + (st * 128 + nt * 16 + ml) * 40 + q * 8);
        acc[nt] = __builtin_amdgcn_mfma_f32_16x16x32_bf16(af.s, bf, acc[nt], 0, 0, 0);
      }
    }
  }
  // f0 epilogue: bias+relu in-place; write bf16 to xbuf
#pragma unroll
  for (int nt = 0; nt < 8; ++nt) {
    float bbv = bb[nt * 16 + ml];
#pragma unroll
    for (int r2 = 0; r2 < 4; ++r2) {
      float v = acc[nt][r2] + bbv; v = fmaxf(v, 0.f);
      acc[nt][r2] = v;
      xbw[(q * 4 + r2) * 136 + nt * 16 + ml] = f2bf(v);
    }
  }
  __syncthreads();                       // (a) xbuf ready, WL free
  short8 f0f[4];
#pragma unroll
  for (int st = 0; st < 4; ++st) f0f[st] = *(const short8*)(xbw + ml * 136 + st * 32 + q * 8);
  for (int i = tid; i < 1280; i += 256) WLf[i] = Wz[i];
  __syncthreads();                       // (b) Wz ready
  // ---- Phase 2: g = relu(z @ Wz + bz) * f0; write bf16 to xbuf ----
#pragma unroll
  for (int nt = 0; nt < 8; ++nt) {
    int col = nt * 16 + ml;
    float bzv = bz[col];
#pragma unroll
    for (int r2 = 0; r2 < 4; ++r2) {
      int row = wv * 16 + q * 4 + r2;
      float zd = bzv;
#pragma unroll
      for (int k = 0; k < 10; ++k) zd += zbufF[row * 12 + k] * WLf[k * 128 + col];
      float g = fmaxf(zd, 0.f) * acc[nt][r2];
      xbw[(q * 4 + r2) * 136 + col] = f2bf(g);
    }
  }
  __syncthreads();                       // (c) g ready; WL(Wz) free
  short8 gf[4];
#pragma unroll
  for (int st = 0; st < 4; ++st) gf[st] = *(const short8*)(xbw + ml * 136 + st * 32 + q * 8);
  stage_W<64>(WL, WgF, tid);
  __syncthreads();                       // (d) WgF ready
  // ---- Phase 3: routing logits (N=64: 3x16 inter + 4 last) + softmax ----
#pragma unroll
  for (int nt = 0; nt < 4; ++nt) acc[nt] = z4;
#pragma unroll
  for (int st = 0; st < 4; ++st) {
#pragma unroll
    for (int nt = 0; nt < 4; ++nt) {
      short8 bf = *(const short8*)(WL + (st * 64 + nt * 16 + ml) * 40 + q * 8);
      acc[nt] = __builtin_amdgcn_mfma_f32_16x16x32_bf16(gf[st], bf, acc[nt], 0, 0, 0);
    }
  }
#pragma unroll
  for (int li = 0; li < 3; ++li) {       // softmax over i (lane bits 2..3); col=i*4+j
#pragma unroll
    for (int r2 = 0; r2 < 4; ++r2) {
      float a = acc[li][r2];
      float m = fmaxf(a, __shfl_xor(a, 4)); m = fmaxf(m, __shfl_xor(m, 8));
      float e = __expf(a - m);
      float s = e; s += __shfl_xor(s, 4); s += __shfl_xor(s, 8);
      pall[(li * 64 + wv * 16 + q * 4 + r2) * 16 + (ml & 3) * 4 + (ml >> 2)] = f2bf(e / s);
    }
  }
#pragma unroll
  for (int r2 = 0; r2 < 4; ++r2) {       // p_last: softmax over m = ml<4
    float a = acc[3][r2];
    float m = fmaxf(a, __shfl_xor(a, 1)); m = fmaxf(m, __shfl_xor(m, 2));
    float e = __expf(a - m);
    float s = e; s += __shfl_xor(s, 1); s += __shfl_xor(s, 2);
    if (ml < 4) plast[(wv * 16 + q * 4 + r2) * 4 + ml] = e / s;
  }

  // ---- Layers: x in registers as bf16 A-frags; combine register-only ----
  short8 xo[4][4];     // x from previous layer, [module][st]
  short8 xin[4][4];    // routed inputs this layer, [module][st]
  f32x4 feat[8];
  for (int l = 0; l < 4; ++l) {
    __syncthreads();   // prev-j3 xbuf written / WL reads done / pall-plast visible
    if (l > 0) {
#pragma unroll
      for (int st = 0; st < 4; ++st) xo[3][st] = *(const short8*)(xbw + ml * 136 + st * 32 + q * 8);
      const unsigned short* prow = pall + ((l - 1) * 64 + wv * 16 + ml) * 16;
#pragma unroll
      for (int j = 0; j < 4; ++j) {
        uint32_t pw0 = *(const uint32_t*)(prow + j * 4);
        uint32_t pw1 = *(const uint32_t*)(prow + j * 4 + 2);
        float p0 = blo(pw0), p1 = bhi(pw0), p2 = blo(pw1), p3 = bhi(pw1);
#pragma unroll
        for (int st = 0; st < 4; ++st) {
          S8 x0, x1, x2, x3, r;
          x0.s = xo[0][st]; x1.s = xo[1][st]; x2.s = xo[2][st]; x3.s = xo[3][st];
#pragma unroll
          for (int w = 0; w < 4; ++w) {
            float lo = p0 * blo(x0.u[w]) + p1 * blo(x1.u[w]) + p2 * blo(x2.u[w]) + p3 * blo(x3.u[w]);
            float hi = p0 * bhi(x0.u[w]) + p1 * bhi(x1.u[w]) + p2 * bhi(x2.u[w]) + p3 * bhi(x3.u[w]);
            r.u[w] = packrne(lo, hi);
          }
          xin[j][st] = r.s;
        }
      }
    } else {
#pragma unroll
      for (int j = 0; j < 4; ++j)
#pragma unroll
        for (int st = 0; st < 4; ++st) xin[j][st] = f0f[st];
    }
    if (l == 3) {
#pragma unroll
      for (int nt = 0; nt < 8; ++nt) feat[nt] = z4;
    }
#pragma unroll
    for (int j = 0; j < 4; ++j) {
      if (j > 0) {
        __syncthreads();   // epi_{j-1} xbuf written; MFMA_{j-1} WL reads done
        if (l < 3) {
#pragma unroll
          for (int st = 0; st < 4; ++st)
            xo[j - 1][st] = *(const short8*)(xbw + ml * 136 + st * 32 + q * 8);
        }
      }
      stage_W<128>(WL, WmF + (l * 4 + j) * 16384, tid);
      __syncthreads();
      f32x4 a[8];
#pragma unroll
      for (int nt = 0; nt < 8; ++nt) a[nt] = z4;
#pragma unroll
      for (int st = 0; st < 4; ++st) {
        short8 av = xin[j][st];
#pragma unroll
        for (int nt = 0; nt < 8; ++nt) {
          short8 bf = *(const short8*)(WL + (st * 128 + nt * 16 + ml) * 40 + q * 8);
          a[nt] = __builtin_amdgcn_mfma_f32_16x16x32_bf16(av, bf, a[nt], 0, 0, 0);
        }
      }
      if (l < 3) {
#pragma unroll
        for (int nt = 0; nt < 8; ++nt) {
          float bmv = bm[(l * 4 + j) * 128 + nt * 16 + ml];
#pragma unroll
          for (int r2 = 0; r2 < 4; ++r2) {
            float v = fmaxf(a[nt][r2] + bmv, 0.f);
            xbw[(q * 4 + r2) * 136 + nt * 16 + ml] = f2bf(v);
          }
        }
      } else {
        float pl[4];
#pragma unroll
        for (int r2 = 0; r2 < 4; ++r2) pl[r2] = plast[(wv * 16 + q * 4 + r2) * 4 + j];
#pragma unroll
        for (int nt = 0; nt < 8; ++nt) {
          float bmv = bm[(3 * 4 + j) * 128 + nt * 16 + ml];
#pragma unroll
          for (int r2 = 0; r2 < 4; ++r2)
            feat[nt][r2] += pl[r2] * fmaxf(a[nt][r2] + bmv, 0.f);
        }
      }
    }
  }

  // ---- Heads ----
  __syncthreads();                  // l3 WL reads done; xbuf free; pall/plast dead
  if (tid < 128) WvF[tid] = Wv[tid];
  if (tid == 128) WvF[128] = bv[0];
  stage_W<128>(WL, Wa1F, tid);
#pragma unroll
  for (int nt = 0; nt < 8; ++nt)
#pragma unroll
    for (int r2 = 0; r2 < 4; ++r2)
      xbw[(q * 4 + r2) * 136 + nt * 16 + ml] = f2bf(feat[nt][r2]);
  __syncthreads();
  // value head: feat . Wv + bv (reduce over cols = lanes)
#pragma unroll
  for (int r2 = 0; r2 < 4; ++r2) {
    float v = 0.f;
#pragma unroll
    for (int nt = 0; nt < 8; ++nt) v += feat[nt][r2] * WvF[nt * 16 + ml];
    v += __shfl_xor(v, 1); v += __shfl_xor(v, 2); v += __shfl_xor(v, 4); v += __shfl_xor(v, 8);
    if (ml == 0) vbuf[wv * 16 + q * 4 + r2] = v + WvF[128];
  }
  // a1 = relu(feat @ Wa1 + ba1)
  short8 ff[4];
#pragma unroll
  for (int st = 0; st < 4; ++st) ff[st] = *(const short8*)(xbw + ml * 136 + st * 32 + q * 8);
#pragma unroll
  for (int nt = 0; nt < 8; ++nt) acc[nt] = z4;
#pragma unroll
  for (int st = 0; st < 4; ++st) {
#pragma unroll
    for (int nt = 0; nt < 8; ++nt) {
      short8 bf = *(const short8*)(WL + (st * 128 + nt * 16 + ml) * 40 + q * 8);
      acc[nt] = __builtin_amdgcn_mfma_f32_16x16x32_bf16(ff[st], bf, acc[nt], 0, 0, 0);
    }
  }
#pragma unroll
  for (int nt = 0; nt < 8; ++nt) {
    float b1v = ba1[nt * 16 + ml];
#pragma unroll
    for (int r2 = 0; r2 < 4; ++r2)
      xbw[(q * 4 + r2) * 136 + nt * 16 + ml] = f2bf(fmaxf(acc[nt][r2] + b1v, 0.f));
  }
  __syncthreads();
  short8 a1f[4];
#pragma unroll
  for (int st = 0; st < 4; ++st) a1f[st] = *(const short8*)(xbw + ml * 136 + st * 32 + q * 8);
  stage_W<16>(WL, Wa2F, tid);
  __syncthreads();
  // adv = a1 @ Wa2 + ba2; out = adv - mean(adv) + value
  f32x4 av = z4;
#pragma unroll
  for (int st = 0; st < 4; ++st) {
    short8 bf = *(const short8*)(WL + (st * 16 + ml) * 40 + q * 8);
    av = __builtin_amdgcn_mfma_f32_16x16x32_bf16(a1f[st], bf, av, 0, 0, 0);
  }
  float ba2v = ba2[ml & 7];
#pragma unroll
  for (int r2 = 0; r2 < 4; ++r2) {
    float a = av[r2] + ba2v;
    float s = a + __shfl_xor(a, 1); s += __shfl_xor(s, 2); s += __shfl_xor(s, 4);
    if (ml < 8)
      out[(size_t)(row0 + wv * 16 + q * 4 + r2) * 8 + ml] = a - s * 0.125f + vbuf[wv * 16 + q * 4 + r2];
  }
}

extern "C" void kernel_launch(void* const* d_in, const int* in_sizes, int n_in,
                              void* d_out, int out_size, void* d_ws, size_t ws_size,
                              hipStream_t stream) {
  const float* o   = (const float*)d_in[0];
  const float* zm  = (const float*)d_in[1];
  const float* cp  = (const float*)d_in[2];
  const float* Wb  = (const float*)d_in[3];
  const float* bb  = (const float*)d_in[4];
  const float* Wz  = (const float*)d_in[5];
  const float* bz  = (const float*)d_in[6];
  const float* Wm  = (const float*)d_in[7];
  const float* bm  = (const float*)d_in[8];
  const float* Wg  = (const float*)d_in[9];
  const float* Wgl = (const float*)d_in[10];
  const float* Wv  = (const float*)d_in[11];
  const float* bv  = (const float*)d_in[12];
  const float* Wa1 = (const float*)d_in[13];
  const float* ba1 = (const float*)d_in[14];
  const float* Wa2 = (const float*)d_in[15];
  const float* ba2 = (const float*)d_in[16];
  unsigned short* wsT = (unsigned short*)d_ws;

  int B = in_sizes[0] / 256;  // 65536

  hipLaunchKernelGGL(prep_weights, dim3(1256), dim3(256), 0, stream,
                     Wb, Wm, Wa1, Wg, Wgl, Wa2, wsT);
  hipLaunchKernelGGL(dueling_fused, dim3(B / 64), dim3(256), 0, stream,
                     o, zm, cp, bb, Wz, bz, bm, Wv, bv, ba1, ba2,
                     wsT, wsT + 32768, wsT + 294912, wsT + 311296, wsT + 319488,
                     (float*)d_out);
}

// Round 3
// 253.337 us; speedup vs baseline: 1.6406x; 1.3568x over previous
//
#include <hip/hip_runtime.h>
#include <stdint.h>

// DuelingQNet fused, bf16 MFMA 16x16x32. BT=64 rows/block, 256 thr (4 waves,
// wave wv owns rows wv*16..+15). x lives in registers as bf16 A-fragments;
// routing combine is register-only packed VALU. Weights pre-shuffled to
// fragment-linear [st][n][32] bf16; staged via global_load_lds (width 16) into
// unpadded LDS. xbuf/pall/plast are wave-private -> only weight stages barrier.
// Dims: B=65536, O=256, Z=9, D=H=128, L=4, M=4, A=8. fp32 in/out.

typedef __attribute__((ext_vector_type(8))) short short8;  // bf16x8 frag (4 VGPR)
typedef __attribute__((ext_vector_type(4))) float f32x4;   // MFMA C/D frag
typedef __attribute__((ext_vector_type(2))) float f32x2;
typedef __attribute__((address_space(1))) const unsigned int u32_g;
typedef __attribute__((address_space(3))) unsigned int u32_l;

__device__ __forceinline__ unsigned short f2bf(float f) {
  union { float f; uint32_t u; } v; v.f = f;
  uint32_t r = v.u + 0x7FFFu + ((v.u >> 16) & 1u);  // RNE
  return (unsigned short)(r >> 16);
}
__device__ __forceinline__ float blo(uint32_t w) { union { uint32_t u; float f; } c; c.u = w << 16; return c.f; }
__device__ __forceinline__ float bhi(uint32_t w) { union { uint32_t u; float f; } c; c.u = w & 0xffff0000u; return c.f; }
__device__ __forceinline__ uint32_t packrne(float lo, float hi) {
  union { float f; uint32_t u; } a, b; a.f = lo; b.f = hi;
  uint32_t ra = a.u + 0x7fffu + ((a.u >> 16) & 1u);
  uint32_t rb = b.u + 0x7fffu + ((b.u >> 16) & 1u);
  return (ra >> 16) | (rb & 0xffff0000u);
}
__device__ __forceinline__ f32x2 unpk2(uint32_t w) {
  f32x2 r; r.x = blo(w); r.y = bhi(w); return r;
}
union S8 { short8 s; uint32_t u[4]; };

// ---- prep: fp32 weights -> bf16 fragment-linear [st][n][32] in workspace ----
// ushort offsets: WbF[8][128][32]@0  WmF 16x[4][128][32]@32768  Wa1F[4][128][32]@294912
//                 WgF[4][64][32]@311296 (n=li*16+i*4+j | 48+m | pad0)  Wa2F[4][16][32]@319488
__global__ void prep_weights(const float* __restrict__ Wb, const float* __restrict__ Wm,
                             const float* __restrict__ Wa1, const float* __restrict__ Wg,
                             const float* __restrict__ Wgl, const float* __restrict__ Wa2,
                             unsigned short* __restrict__ ws) {
  int idx = blockIdx.x * 256 + threadIdx.x;
  if (idx >= 321536) return;
  unsigned short v;
  if (idx < 32768) {
    int st = idx >> 12, n = (idx >> 5) & 127, kk = idx & 31;
    v = f2bf(Wb[(st * 32 + kk) * 128 + n]);
  } else if (idx < 294912) {
    int t = idx - 32768; int lj = t >> 14; int g = t & 16383;
    int st = g >> 12, n = (g >> 5) & 127, kk = g & 31;
    v = f2bf(Wm[lj * 16384 + (st * 32 + kk) * 128 + n]);
  } else if (idx < 311296) {
    int t = idx - 294912; int st = t >> 12, n = (t >> 5) & 127, kk = t & 31;
    v = f2bf(Wa1[(st * 32 + kk) * 128 + n]);
  } else if (idx < 319488) {
    int t = idx - 311296; int st = t >> 11, n = (t >> 5) & 63, kk = t & 31;
    int k = st * 32 + kk;
    if (n < 48)      v = f2bf(Wg[(n >> 4) * 2048 + k * 16 + (n & 15)]);
    else if (n < 52) v = f2bf(Wgl[k * 4 + (n - 48)]);
    else             v = 0;
  } else {
    int t = idx - 319488; int st = t >> 9, n = (t >> 5) & 15, kk = t & 31;
    v = (n < 8) ? f2bf(Wa2[(st * 32 + kk) * 8 + n]) : (unsigned short)0;
  }
  ws[idx] = v;
}

__device__ __forceinline__ void gld16(const void* g, void* l) {
  __builtin_amdgcn_global_load_lds((u32_g*)g, (u32_l*)l, 16, 0, 0);
}

// async-stage BYTES of frag-linear weights into LDS (layout preserved).
// HW writes lds at wave-uniform base + lane*16; lane offset goes on gptr only.
template <int BYTES>
__device__ __forceinline__ void stageW(void* wl, const unsigned short* __restrict__ src, int tid) {
  const char* g = (const char*)src;
  char* l = (char*)wl;
  int wvoff = (tid >> 6) << 10;         // wave-uniform
  int goff = wvoff | ((tid & 63) << 4);
#pragma unroll
  for (int it = 0; it < BYTES / 4096; ++it)
    gld16(g + it * 4096 + goff, l + it * 4096 + wvoff);
}

// one 16-row x 128-col module GEMM from staged WL (unpadded frag-linear)
__device__ __forceinline__ void gemm128(const short8 xin[4], const unsigned short* WL,
                                        int q, int ml, f32x4 a[8]) {
#pragma unroll
  for (int nt = 0; nt < 8; ++nt) a[nt] = (f32x4){0.f, 0.f, 0.f, 0.f};
#pragma unroll
  for (int st = 0; st < 4; ++st) {
#pragma unroll
    for (int nt = 0; nt < 8; ++nt) {
      short8 bf = *(const short8*)(WL + (st * 128 + nt * 16 + ml) * 32 + q * 8);
      a[nt] = __builtin_amdgcn_mfma_f32_16x16x32_bf16(xin[st], bf, a[nt], 0, 0, 0);
    }
  }
}

// xin_j = sum_i p[i][j] * xo_i for all j, packed bf16x2 math in f32x2
__device__ __forceinline__ void combine_layer(const short8 xo[4][4],
                                              const unsigned short* __restrict__ prow,
                                              short8 xin[4][4]) {
  float p[4][4];
#pragma unroll
  for (int j = 0; j < 4; ++j) {
    uint32_t pw0 = *(const uint32_t*)(prow + j * 4);
    uint32_t pw1 = *(const uint32_t*)(prow + j * 4 + 2);
    p[j][0] = blo(pw0); p[j][1] = bhi(pw0); p[j][2] = blo(pw1); p[j][3] = bhi(pw1);
  }
#pragma unroll
  for (int st = 0; st < 4; ++st) {
    S8 x0, x1, x2, x3;
    x0.s = xo[0][st]; x1.s = xo[1][st]; x2.s = xo[2][st]; x3.s = xo[3][st];
    S8 r0, r1, r2, r3;
#pragma unroll
    for (int w = 0; w < 4; ++w) {
      f32x2 u0 = unpk2(x0.u[w]), u1 = unpk2(x1.u[w]), u2 = unpk2(x2.u[w]), u3 = unpk2(x3.u[w]);
      f32x2 s0 = p[0][0] * u0 + p[0][1] * u1 + p[0][2] * u2 + p[0][3] * u3;
      f32x2 s1 = p[1][0] * u0 + p[1][1] * u1 + p[1][2] * u2 + p[1][3] * u3;
      f32x2 s2 = p[2][0] * u0 + p[2][1] * u1 + p[2][2] * u2 + p[2][3] * u3;
      f32x2 s3 = p[3][0] * u0 + p[3][1] * u1 + p[3][2] * u2 + p[3][3] * u3;
      r0.u[w] = packrne(s0.x, s0.y); r1.u[w] = packrne(s1.x, s1.y);
      r2.u[w] = packrne(s2.x, s2.y); r3.u[w] = packrne(s3.x, s3.y);
    }
    xin[0][st] = r0.s; xin[1][st] = r1.s; xin[2][st] = r2.s; xin[3][st] = r3.s;
  }
}

__global__ __attribute__((amdgpu_flat_work_group_size(256, 256), amdgpu_waves_per_eu(2, 2)))
void dueling_fused(
    const float* __restrict__ o, const float* __restrict__ zmap, const float* __restrict__ coll,
    const float* __restrict__ bb, const float* __restrict__ Wz, const float* __restrict__ bz,
    const float* __restrict__ bm, const float* __restrict__ Wv, const float* __restrict__ bv,
    const float* __restrict__ ba1, const float* __restrict__ ba2,
    const unsigned short* __restrict__ WbF, const unsigned short* __restrict__ WmF,
    const unsigned short* __restrict__ Wa1F, const unsigned short* __restrict__ WgF,
    const unsigned short* __restrict__ Wa2F, float* __restrict__ out)
{
  // LDS 57344 B: WL 32768 | xbuf 17408 | pall 6144 (ovl zbuf, WvF) | plast 1024 (ovl vbuf)
  __shared__ __align__(16) unsigned char smem[57344];
  unsigned short* WL    = (unsigned short*)(smem);
  float*          WLf   = (float*)(smem);                    // fp32 overlay (Wz)
  unsigned short* xbuf  = (unsigned short*)(smem + 32768);   // per-wave [16][136] bf16
  unsigned short* pall  = (unsigned short*)(smem + 50176);   // [3][64][16] bf16, idx j*4+i (wave-private rows)
  float*          zbufF = (float*)(smem + 50176);            // [64][12] (dead before pall)
  float*          WvF   = (float*)(smem + 50176);            // [129]    (after pall dead)
  float*          plast = (float*)(smem + 56320);            // [64][4]  (wave-private rows)
  float*          vbuf  = (float*)(smem + 56320);            // [64]     (after plast dead)

  const int tid = threadIdx.x;
  const int wv  = tid >> 6;
  const int lane = tid & 63;
  const int q   = lane >> 4;     // quad: A-frag k chunk / C-frag row group
  const int ml  = lane & 15;     // A-row / B-col / C-col
  const int row0 = blockIdx.x * 64;
  unsigned short* xbw = xbuf + wv * 2176;   // wave-private [16][136]

  // z_in staging (cross-wave; covered by barriers before phase 2)
  for (int i = tid; i < 640; i += 256) {
    if (i < 576) { int r = i / 9, c = i - r * 9; zbufF[r * 12 + c] = zmap[(row0 + r) * 9 + c]; }
    else         { int r = i - 576; zbufF[r * 12 + 9] = coll[row0 + r]; }
  }

  const f32x4 z4 = {0.f, 0.f, 0.f, 0.f};

  // ---- Phase 1: f0 = relu(o @ Wb + bb), K=256 in two 32KB halves ----
  f32x4 acc[8];
#pragma unroll
  for (int nt = 0; nt < 8; ++nt) acc[nt] = z4;
  const float* orow = o + (size_t)(row0 + wv * 16 + ml) * 256;
#pragma unroll
  for (int kh = 0; kh < 2; ++kh) {
    float4 ov[8];
#pragma unroll
    for (int st = 0; st < 4; ++st) {
      const float* src = orow + kh * 128 + st * 32 + q * 8;
      ov[st * 2]     = *(const float4*)(src);
      ov[st * 2 + 1] = *(const float4*)(src + 4);
    }
    if (kh) __syncthreads();            // all waves done with half 0
    stageW<32768>(WL, WbF + kh * 16384, tid);
    __syncthreads();                    // WL half ready (vmcnt drained by barrier)
#pragma unroll
    for (int st = 0; st < 4; ++st) {
      S8 af;
      af.u[0] = packrne(ov[st*2].x, ov[st*2].y);     af.u[1] = packrne(ov[st*2].z, ov[st*2].w);
      af.u[2] = packrne(ov[st*2+1].x, ov[st*2+1].y); af.u[3] = packrne(ov[st*2+1].z, ov[st*2+1].w);
#pragma unroll
      for (int nt = 0; nt < 8; ++nt) {
        short8 bf = *(const short8*)(WL + (st * 128 + nt * 16 + ml) * 32 + q * 8);
        acc[nt] = __builtin_amdgcn_mfma_f32_16x16x32_bf16(af.s, bf, acc[nt], 0, 0, 0);
      }
    }
  }
  // f0 epilogue: bias+relu; keep fp32 in acc (for g), bf16 copy in xbw
#pragma unroll
  for (int nt = 0; nt < 8; ++nt) {
    float bbv = bb[nt * 16 + ml];
#pragma unroll
    for (int r2 = 0; r2 < 4; ++r2) {
      float v = fmaxf(acc[nt][r2] + bbv, 0.f);
      acc[nt][r2] = v;
      xbw[(q * 4 + r2) * 136 + nt * 16 + ml] = f2bf(v);
    }
  }
  __syncthreads();                      // WL (Wb half 1) reads done everywhere
  short8 f0f[4];
#pragma unroll
  for (int st = 0; st < 4; ++st) f0f[st] = *(const short8*)(xbw + ml * 136 + st * 32 + q * 8);
  for (int i = tid; i < 1280; i += 256) WLf[i] = Wz[i];
  __syncthreads();                      // Wz + zbuf visible
  // ---- Phase 2: g = relu(z @ Wz + bz) * f0 -> xbw ----
#pragma unroll
  for (int nt = 0; nt < 8; ++nt) {
    int col = nt * 16 + ml;
    float bzv = bz[col];
#pragma unroll
    for (int r2 = 0; r2 < 4; ++r2) {
      int row = wv * 16 + q * 4 + r2;
      float zd = bzv;
#pragma unroll
      for (int k = 0; k < 10; ++k) zd += zbufF[row * 12 + k] * WLf[k * 128 + col];
      xbw[(q * 4 + r2) * 136 + col] = f2bf(fmaxf(zd, 0.f) * acc[nt][r2]);
    }
  }
  __syncthreads();                      // WLf (Wz) reads done
  short8 gf[4];
#pragma unroll
  for (int st = 0; st < 4; ++st) gf[st] = *(const short8*)(xbw + ml * 136 + st * 32 + q * 8);
  stageW<16384>(WL, WgF, tid);
  __syncthreads();                      // WgF ready
  // ---- Phase 3: routing logits (N=64) + softmaxes ----
#pragma unroll
  for (int nt = 0; nt < 4; ++nt) acc[nt] = z4;
#pragma unroll
  for (int st = 0; st < 4; ++st) {
#pragma unroll
    for (int nt = 0; nt < 4; ++nt) {
      short8 bf = *(const short8*)(WL + (st * 64 + nt * 16 + ml) * 32 + q * 8);
      acc[nt] = __builtin_amdgcn_mfma_f32_16x16x32_bf16(gf[st], bf, acc[nt], 0, 0, 0);
    }
  }
#pragma unroll
  for (int li = 0; li < 3; ++li) {      // softmax over i (lane bits 2..3); col = i*4+j
#pragma unroll
    for (int r2 = 0; r2 < 4; ++r2) {
      float a = acc[li][r2];
      float m = fmaxf(a, __shfl_xor(a, 4)); m = fmaxf(m, __shfl_xor(m, 8));
      float e = __expf(a - m);
      float s = e; s += __shfl_xor(s, 4); s += __shfl_xor(s, 8);
      pall[(li * 64 + wv * 16 + q * 4 + r2) * 16 + (ml & 3) * 4 + (ml >> 2)] = f2bf(e / s);
    }
  }
#pragma unroll
  for (int r2 = 0; r2 < 4; ++r2) {      // p_last: softmax over m = ml<4
    float a = acc[3][r2];
    float m = fmaxf(a, __shfl_xor(a, 1)); m = fmaxf(m, __shfl_xor(m, 2));
    float e = __expf(a - m);
    float s = e; s += __shfl_xor(s, 1); s += __shfl_xor(s, 2);
    if (ml < 4) plast[(wv * 16 + q * 4 + r2) * 4 + ml] = e / s;
  }

  // ---- Layer 0 (peeled): all modules consume f0 ----
  short8 xo[4][4];
  f32x4 a[8];
#pragma unroll
  for (int j = 0; j < 4; ++j) {
    if (j > 0) {
#pragma unroll
      for (int st = 0; st < 4; ++st) xo[j - 1][st] = *(const short8*)(xbw + ml * 136 + st * 32 + q * 8);
    }
    __syncthreads();                    // prev WL reads done
    stageW<32768>(WL, WmF + j * 16384, tid);
    __syncthreads();                    // WL ready
    gemm128(f0f, WL, q, ml, a);
#pragma unroll
    for (int nt = 0; nt < 8; ++nt) {
      float bmv = bm[j * 128 + nt * 16 + ml];
#pragma unroll
      for (int r2 = 0; r2 < 4; ++r2)
        xbw[(q * 4 + r2) * 136 + nt * 16 + ml] = f2bf(fmaxf(a[nt][r2] + bmv, 0.f));
    }
  }

  // ---- Layers 1..2 (runtime loop; xin precompute frees xo progressively) ----
  short8 xin[4][4];
  for (int l = 1; l <= 2; ++l) {
#pragma unroll
    for (int st = 0; st < 4; ++st) xo[3][st] = *(const short8*)(xbw + ml * 136 + st * 32 + q * 8);
    combine_layer(xo, pall + ((l - 1) * 64 + wv * 16 + ml) * 16, xin);
#pragma unroll
    for (int j = 0; j < 4; ++j) {
      if (j > 0) {
#pragma unroll
        for (int st = 0; st < 4; ++st) xo[j - 1][st] = *(const short8*)(xbw + ml * 136 + st * 32 + q * 8);
      }
      __syncthreads();
      stageW<32768>(WL, WmF + (l * 4 + j) * 16384, tid);
      __syncthreads();
      gemm128(xin[j], WL, q, ml, a);
#pragma unroll
      for (int nt = 0; nt < 8; ++nt) {
        float bmv = bm[(l * 4 + j) * 128 + nt * 16 + ml];
#pragma unroll
        for (int r2 = 0; r2 < 4; ++r2)
          xbw[(q * 4 + r2) * 136 + nt * 16 + ml] = f2bf(fmaxf(a[nt][r2] + bmv, 0.f));
      }
    }
  }

  // ---- Layer 3 (peeled): feature = sum_j p_last[j] * relu(. . .) ----
  f32x4 feat[8];
  {
#pragma unroll
    for (int st = 0; st < 4; ++st) xo[3][st] = *(const short8*)(xbw + ml * 136 + st * 32 + q * 8);
    combine_layer(xo, pall + (2 * 64 + wv * 16 + ml) * 16, xin);
#pragma unroll
    for (int nt = 0; nt < 8; ++nt) feat[nt] = z4;
#pragma unroll
    for (int j = 0; j < 4; ++j) {
      __syncthreads();
      stageW<32768>(WL, WmF + (12 + j) * 16384, tid);
      __syncthreads();
      gemm128(xin[j], WL, q, ml, a);
      float pl[4];
#pragma unroll
      for (int r2 = 0; r2 < 4; ++r2) pl[r2] = plast[(wv * 16 + q * 4 + r2) * 4 + j];
#pragma unroll
      for (int nt = 0; nt < 8; ++nt) {
        float bmv = bm[(12 + j) * 128 + nt * 16 + ml];
#pragma unroll
        for (int r2 = 0; r2 < 4; ++r2)
          feat[nt][r2] += pl[r2] * fmaxf(a[nt][r2] + bmv, 0.f);
      }
    }
  }

  // ---- Heads ----
  __syncthreads();                      // l3 WL reads done; pall/plast dead
  if (tid < 128) WvF[tid] = Wv[tid];
  if (tid == 128) WvF[128] = bv[0];
  stageW<32768>(WL, Wa1F, tid);
#pragma unroll
  for (int nt = 0; nt < 8; ++nt)
#pragma unroll
    for (int r2 = 0; r2 < 4; ++r2)
      xbw[(q * 4 + r2) * 136 + nt * 16 + ml] = f2bf(feat[nt][r2]);
  __syncthreads();                      // Wa1 ready + WvF visible
  // value head: feat . Wv + bv (reduce over cols = lanes)
#pragma unroll
  for (int r2 = 0; r2 < 4; ++r2) {
    float v = 0.f;
#pragma unroll
    for (int nt = 0; nt < 8; ++nt) v += feat[nt][r2] * WvF[nt * 16 + ml];
    v += __shfl_xor(v, 1); v += __shfl_xor(v, 2); v += __shfl_xor(v, 4); v += __shfl_xor(v, 8);
    if (ml == 0) vbuf[wv * 16 + q * 4 + r2] = v + WvF[128];
  }
  // a1 = relu(feat @ Wa1 + ba1)
  short8 ff[4];
#pragma unroll
  for (int st = 0; st < 4; ++st) ff[st] = *(const short8*)(xbw + ml * 136 + st * 32 + q * 8);
  gemm128(ff, WL, q, ml, a);
#pragma unroll
  for (int nt = 0; nt < 8; ++nt) {
    float b1v = ba1[nt * 16 + ml];
#pragma unroll
    for (int r2 = 0; r2 < 4; ++r2)
      xbw[(q * 4 + r2) * 136 + nt * 16 + ml] = f2bf(fmaxf(a[nt][r2] + b1v, 0.f));
  }
  __syncthreads();                      // Wa1 reads done
  stageW<4096>(WL, Wa2F, tid);
  __syncthreads();                      // Wa2 ready
  short8 a1f[4];
#pragma unroll
  for (int st = 0; st < 4; ++st) a1f[st] = *(const short8*)(xbw + ml * 136 + st * 32 + q * 8);
  // adv = a1 @ Wa2 + ba2; out = adv - mean(adv) + value
  f32x4 av = z4;
#pragma unroll
  for (int st = 0; st < 4; ++st) {
    short8 bf = *(const short8*)(WL + (st * 16 + ml) * 32 + q * 8);
    av = __builtin_amdgcn_mfma_f32_16x16x32_bf16(a1f[st], bf, av, 0, 0, 0);
  }
  float ba2v = ba2[ml & 7];
#pragma unroll
  for (int r2 = 0; r2 < 4; ++r2) {
    float aa = av[r2] + ba2v;
    float s = aa + __shfl_xor(aa, 1); s += __shfl_xor(s, 2); s += __shfl_xor(s, 4);
    if (ml < 8)
      out[(size_t)(row0 + wv * 16 + q * 4 + r2) * 8 + ml] = aa - s * 0.125f + vbuf[wv * 16 + q * 4 + r2];
  }
}

extern "C" void kernel_launch(void* const* d_in, const int* in_sizes, int n_in,
                              void* d_out, int out_size, void* d_ws, size_t ws_size,
                              hipStream_t stream) {
  const float* o   = (const float*)d_in[0];
  const float* zm  = (const float*)d_in[1];
  const float* cp  = (const float*)d_in[2];
  const float* Wb  = (const float*)d_in[3];
  const float* bb  = (const float*)d_in[4];
  const float* Wz  = (const float*)d_in[5];
  const float* bz  = (const float*)d_in[6];
  const float* Wm  = (const float*)d_in[7];
  const float* bm  = (const float*)d_in[8];
  const float* Wg  = (const float*)d_in[9];
  const float* Wgl = (const float*)d_in[10];
  const float* Wv  = (const float*)d_in[11];
  const float* bv  = (const float*)d_in[12];
  const float* Wa1 = (const float*)d_in[13];
  const float* ba1 = (const float*)d_in[14];
  const float* Wa2 = (const float*)d_in[15];
  const float* ba2 = (const float*)d_in[16];
  unsigned short* wsT = (unsigned short*)d_ws;

  int B = in_sizes[0] / 256;  // 65536

  hipLaunchKernelGGL(prep_weights, dim3(1256), dim3(256), 0, stream,
                     Wb, Wm, Wa1, Wg, Wgl, Wa2, wsT);
  hipLaunchKernelGGL(dueling_fused, dim3(B / 64), dim3(256), 0, stream,
                     o, zm, cp, bb, Wz, bz, bm, Wv, bv, ba1, ba2,
                     wsT, wsT + 32768, wsT + 294912, wsT + 311296, wsT + 319488,
                     (float*)d_out);
}